// Round 4
// baseline (25.865 us; speedup 1.0000x reference)
//
#include <hip/hip_runtime.h>
#include <cmath>

constexpr int B_ = 16, N_ = 10, H_ = 400, W_ = 400;
constexpr int HW = H_ * W_;              // 160000
constexpr int BN = B_ * N_;              // 160
constexpr int SPLITS = 16;               // stripes per image
constexpr int CHUNK4 = HW / 4 / SPLITS;  // 2500 float4s per stripe
constexpr int BS = B_ * SPLITS;          // 256 (b,s) pairs

// ws layout (all partials; every slot written every call -> no zeroing):
//   [0, BN*SPLITS)                overlap partials, slot = bn*SPLITS+s
//   [BN*SPLITS, 2*BN*SPLITS)      inter partials
//   [2*BN*SPLITS, +B_*SPLITS)     tgt_area partials (from n==0 blocks)
constexpr int OFF_I = BN * SPLITS;
constexpr int OFF_T = 2 * BN * SPLITS;

// XCD-aware decomposition: blockIdx.x = n*BS + (b*SPLITS + s).
// All 10 n-replicas of one (b,s) tm-stripe share id%8 -> same XCD ->
// the 40KB tm stripe stays in that XCD's L2 across all 10 reads.
__global__ void __launch_bounds__(256)
fused_k(const float4* __restrict__ om, const float4* __restrict__ tm,
        const float* __restrict__ bboxes, float* __restrict__ ws) {
    __shared__ float smO[4], smI[4], smT[4];
    int bs = blockIdx.x % BS;
    int n  = blockIdx.x / BS;
    int b  = bs / SPLITS;
    int s  = bs % SPLITS;
    int bn = b * N_ + n;

    float4 bb = reinterpret_cast<const float4*>(bboxes)[bn];
    int x1 = (int)floorf(bb.x), y1 = (int)floorf(bb.y);
    int x2 = (int)floorf(bb.z), y2 = (int)floorf(bb.w);

    const float4* omp = om + (size_t)bn * (HW / 4) + (size_t)s * CHUNK4;
    const float4* tmp = tm + (size_t)b  * (HW / 4) + (size_t)s * CHUNK4;
    int fbase = s * CHUNK4 * 4;  // flat float index base within the image

    float accO = 0.0f, accI = 0.0f, accT = 0.0f;
    for (int i = threadIdx.x; i < CHUNK4; i += 256) {
        float4 o = omp[i];
        float4 t = tmp[i];
        accO += o.x * t.x + o.y * t.y + o.z * t.z + o.w * t.w;
        accT += t.x + t.y + t.z + t.w;
        int fi = fbase + i * 4;
        int r  = fi / W_;          // W_=400: float4 spans 4 cols of one row
        int c  = fi - r * W_;
        if (r >= y1 && r < y2) {
            float ix = (c     >= x1 && c     < x2) ? t.x : 0.0f;
            float iy = (c + 1 >= x1 && c + 1 < x2) ? t.y : 0.0f;
            float iz = (c + 2 >= x1 && c + 2 < x2) ? t.z : 0.0f;
            float iw = (c + 3 >= x1 && c + 3 < x2) ? t.w : 0.0f;
            accI += ix + iy + iz + iw;
        }
    }
#pragma unroll
    for (int off = 32; off > 0; off >>= 1) {
        accO += __shfl_down(accO, off, 64);
        accI += __shfl_down(accI, off, 64);
        accT += __shfl_down(accT, off, 64);
    }
    int lane = threadIdx.x & 63, wid = threadIdx.x >> 6;
    if (lane == 0) { smO[wid] = accO; smI[wid] = accI; smT[wid] = accT; }
    __syncthreads();
    if (threadIdx.x == 0) {
        int slot = bn * SPLITS + s;
        ws[slot]         = smO[0] + smO[1] + smO[2] + smO[3];
        ws[OFF_I + slot] = smI[0] + smI[1] + smI[2] + smI[3];
        if (n == 0)
            ws[OFF_T + b * SPLITS + s] = smT[0] + smT[1] + smT[2] + smT[3];
    }
}

__global__ void __launch_bounds__(256)
finalize_k(const float* __restrict__ bboxes, const float* __restrict__ ws,
           float* __restrict__ out) {
    int bn = threadIdx.x;
    if (bn >= BN) return;
    int b = bn / N_;
    float ov = 0.0f, inter = 0.0f, tgt = 0.0f;
#pragma unroll
    for (int s = 0; s < SPLITS; ++s) {
        ov    += ws[bn * SPLITS + s];
        inter += ws[OFF_I + bn * SPLITS + s];
        tgt   += ws[OFF_T + b * SPLITS + s];
    }
    float4 bb = reinterpret_cast<const float4*>(bboxes)[bn];
    int x1 = (int)floorf(bb.x), y1 = (int)floorf(bb.y);
    int x2 = (int)floorf(bb.z), y2 = (int)floorf(bb.w);
    float cr = (float)max(0, min(y2, H_) - max(y1, 0));
    float cc = (float)max(0, min(x2, W_) - max(x1, 0));
    float box_area = cr * cc;
    float iou = inter / (box_area + tgt - inter + 1e-8f);
    out[bn * 2 + 0] = ov;
    out[bn * 2 + 1] = iou;
}

extern "C" void kernel_launch(void* const* d_in, const int* in_sizes, int n_in,
                              void* d_out, int out_size, void* d_ws, size_t ws_size,
                              hipStream_t stream) {
    const float*  bboxes = (const float*)d_in[0];
    const float4* om     = (const float4*)d_in[1];
    const float4* tm     = (const float4*)d_in[2];
    float* out = (float*)d_out;
    float* ws  = (float*)d_ws;

    fused_k<<<BN * SPLITS, 256, 0, stream>>>(om, tm, bboxes, ws);
    finalize_k<<<1, 256, 0, stream>>>(bboxes, ws, out);
}